// Round 1
// 791.266 us; speedup vs baseline: 1.0144x; 1.0144x over previous
//
#include <hip/hip_runtime.h>

#define USER_NUM 500000
#define BATCH 4096
#define NF 64
#define DIM 256
#define MEMN 32
#define ATTN 256

typedef short bf16x8 __attribute__((ext_vector_type(8)));
typedef float f32x4 __attribute__((ext_vector_type(4)));

// ---------- bf16 helpers (RNE) ----------
__device__ __forceinline__ unsigned short f2bf(float f) {
    unsigned u = __float_as_uint(f);
    u += 0x7FFFu + ((u >> 16) & 1u);
    return (unsigned short)(u >> 16);
}
__device__ __forceinline__ float bf2f(unsigned short s) {
    return __uint_as_float(((unsigned)s) << 16);
}
__device__ __forceinline__ bf16x8 as_frag(uint4 v) {
    return __builtin_bit_cast(bf16x8, v);
}

__device__ __forceinline__ float block_reduce_sum(float v, float* scr) {
#pragma unroll
    for (int o = 32; o; o >>= 1) v += __shfl_xor(v, o, 64);
    __syncthreads();
    if ((threadIdx.x & 63) == 0) scr[threadIdx.x >> 6] = v;
    __syncthreads();
    return scr[0] + scr[1] + scr[2] + scr[3];
}

// two reductions sharing one barrier pair
__device__ __forceinline__ float2 block_reduce_sum2(float a, float b, float* scr) {
#pragma unroll
    for (int o = 32; o; o >>= 1) {
        a += __shfl_xor(a, o, 64);
        b += __shfl_xor(b, o, 64);
    }
    __syncthreads();
    if ((threadIdx.x & 63) == 0) {
        scr[(threadIdx.x >> 6) * 2]     = a;
        scr[(threadIdx.x >> 6) * 2 + 1] = b;
    }
    __syncthreads();
    float2 r;
    r.x = scr[0] + scr[2] + scr[4] + scr[6];
    r.y = scr[1] + scr[3] + scr[5] + scr[7];
    return r;
}

// ---------- ws offsets (bytes) ----------
#define WS_AK    0u            // float [4096][64][32]     = 33554432  (holds exp(att_key))
#define WS_FE    33554432u     // bf16  [4096][64][256]    = 134217728 (masked fe)
#define WS_KEYT  167772160u    // bf16  [32][256]          = 16384  (KeyT[m][d])
#define WS_MEMT  167788544u    // bf16  [256][32]          = 16384  (MemT[d][m])
#define WS_WATT  167804928u    // bf16  [8][256][32]       = 131072 (WA k-tiled: [kt][a][kk])
#define WS_PART  167936000u    // float [8][2048]          = 65536
#define WS_SSUM  168001536u    // float [2048]             = 8192   (holds 1/sum)

// =============== kernel P: KeyT only (katt's sole prerequisite) ===============
__global__ __launch_bounds__(256) void kprep(const float* __restrict__ Key,
                                             unsigned short* __restrict__ keyT) {
    int gid = blockIdx.x * 256 + threadIdx.x;   // grid = 32 blocks -> 8192 exactly
    int m = gid >> 8, d = gid & 255;
    keyT[gid] = f2bf(Key[d * 32 + m]);          // KeyT[m][d] = Key[d][m]
}

// =============== kernel A: eak[b,f,m]=exp(att_key) + fe_bf16 dump (one block per b) ===============
// LDS: cross bf16 [64][264] @0 (33792) | uidn f32 [256] @33792 | scr @34816 -> 34880 dynamic
__global__ __launch_bounds__(256, 4) void katt(const int* __restrict__ input_u,
                                               const int* __restrict__ input_uf,
                                               const float* __restrict__ uidW,
                                               const unsigned short* __restrict__ keyT_ws,
                                               unsigned short* __restrict__ fe_ws,
                                               float* __restrict__ ak) {
    extern __shared__ char smem[];
    float* uidn = (float*)(smem + 33792);
    float* scr  = (float*)(smem + 34816);
    const int b = blockIdx.x, t = threadIdx.x;
    const int w = t >> 6, l = t & 63, q = l >> 4;

    // friend indices via register + shfl (no LDS, no barrier before the gather)
    int iu   = input_u[b];
    int myuf = input_uf[b * NF + w * 16 + (l & 15)];
    float uv = uidW[(size_t)iu * DIM + t];

    // issue all 16 friend-row gathers ASAP; latency overlaps the uid normalize below
    float4 fe[16];
#pragma unroll
    for (int i = 0; i < 16; i++) {
        int idx = __shfl(myuf, i, 64);
        fe[i] = ((const float4*)(uidW + (size_t)idx * DIM))[l];
    }

    // uid row L2 normalize (its barriers absorb the gather latency)
    float ss = block_reduce_sum(uv * uv, scr);
    float inv = 1.0f / fmaxf(sqrtf(ss), 1e-12f);
    uidn[t] = uv * inv;
    __syncthreads();

    float4 un4 = *(const float4*)(uidn + l * 4);
#pragma unroll
    for (int i = 0; i < 16; i++) {
        int f = w * 16 + i;
        float mk = (__shfl(myuf, i, 64) != USER_NUM) ? 1.0f : 0.0f;
        float x = fe[i].x * mk, y = fe[i].y * mk, z = fe[i].z * mk, ww = fe[i].w * mk;
        float s2 = x * x + y * y + z * z + ww * ww;
#pragma unroll
        for (int o = 32; o; o >>= 1) s2 += __shfl_xor(s2, o, 64);
        float rn = 1.0f / fmaxf(sqrtf(s2), 1e-12f);
        // masked fe -> ws (bf16, sequential)
        ushort4 fb;
        fb.x = f2bf(x); fb.y = f2bf(y); fb.z = f2bf(z); fb.w = f2bf(ww);
        *(ushort4*)(fe_ws + (size_t)b * 16384 + f * 256 + l * 4) = fb;
        // cross = uid_n * fe_n -> LDS
        ushort4 o4;
        o4.x = f2bf(un4.x * x * rn);
        o4.y = f2bf(un4.y * y * rn);
        o4.z = f2bf(un4.z * z * rn);
        o4.w = f2bf(un4.w * ww * rn);
        *(ushort4*)(smem + f * 528 + l * 8) = o4;
    }
    __syncthreads();

    // MFMA: att_key[64f x 32m] = cross[64x256] @ Key[256x32]; wave w owns f-tile w.
    const uint4* kp = (const uint4*)keyT_ws;   // [m][d] rows of 512B = 32 uint4
    f32x4 acc0 = {0.f, 0.f, 0.f, 0.f}, acc1 = {0.f, 0.f, 0.f, 0.f};
#pragma unroll
    for (int kt = 0; kt < 8; kt++) {
        bf16x8 aF = *(const bf16x8*)(smem + (w * 16 + (l & 15)) * 528 + kt * 64 + q * 16);
        bf16x8 b0 = as_frag(kp[(l & 15) * 32 + kt * 4 + q]);
        bf16x8 b1 = as_frag(kp[((l & 15) + 16) * 32 + kt * 4 + q]);
        acc0 = __builtin_amdgcn_mfma_f32_16x16x32_bf16(aF, b0, acc0, 0, 0, 0);
        acc1 = __builtin_amdgcn_mfma_f32_16x16x32_bf16(aF, b1, acc1, 0, 0, 0);
    }
    {
        int fbase = w * 16 + q * 4;
        int m = l & 15;
#pragma unroll
        for (int r = 0; r < 4; r++) {
            // store exp(att_key): computed once here instead of twice downstream
            ak[((size_t)b * NF + fbase + r) * MEMN + m]      = __expf(acc0[r]);
            ak[((size_t)b * NF + fbase + r) * MEMN + 16 + m] = __expf(acc1[r]);
        }
    }
}

// =============== kernel B1/B2: ssum[f,m] = 1 / sum_b eak[b,f,m] ===============
__global__ __launch_bounds__(256) void ksum1(const float* __restrict__ ak, float* __restrict__ part) {
    __shared__ float pl[256];
    int bid = blockIdx.x;               // 512 = 64 f * 8 chunks
    int f = bid >> 3, c = bid & 7;
    int t = threadIdx.x, m = t & 31, g = t >> 5;
    float s = 0.f;
    size_t base = ((size_t)(c * 512 + g) * NF + f) * MEMN + m;
#pragma unroll 8
    for (int i = 0; i < 64; i++) {      // b = c*512 + g + 8*i
        s += ak[base];
        base += (size_t)8 * NF * MEMN;
    }
    pl[t] = s;
    __syncthreads();
    if (t < 32) {
        float tot = 0.f;
#pragma unroll
        for (int gg = 0; gg < 8; gg++) tot += pl[gg * 32 + t];
        part[c * 2048 + f * 32 + t] = tot;
    }
}
// ksum2 also converts Mem/WA to bf16 tiles (only kmain needs them)
__global__ __launch_bounds__(256) void ksum2(const float* __restrict__ part,
                                             float* __restrict__ ssum,
                                             const float* __restrict__ Mem,
                                             const float* __restrict__ WA,
                                             unsigned short* __restrict__ memT,
                                             unsigned short* __restrict__ watt) {
    int fm = blockIdx.x * 256 + threadIdx.x;   // 8 blocks -> 2048 threads
    float s = 0.f;
#pragma unroll
    for (int c = 0; c < 8; c++) s += part[c * 2048 + fm];
    ssum[fm] = 1.0f / s;                       // store reciprocal
    // MemT[d][m] = Mem[m][d]
    for (int e = fm; e < 8192; e += 2048) {
        int d = e >> 5, m = e & 31;
        memT[e] = f2bf(Mem[m * 256 + d]);
    }
    // watt[kt][a][kk] = WA[kt*32+kk][a]
    for (int e = fm; e < 65536; e += 2048) {
        int kt = e >> 13, r = e & 8191, a = r >> 5, kk = r & 31;
        watt[e] = f2bf(WA[(kt * 32 + kk) * 256 + a]);
    }
}

// =============== kernel C: everything after the batch softmax (one block per b) ===============
// LDS layout (bytes):
//   f1f2 bf16 [64][264] @0      (33792)   f1 then overwritten by f2
//   am   bf16 [64][40]  @33792  (5120)
//   jpart f32 [4][64]   @38912  (1024)
//   wL    f32 [64]      @39936  (256)
//   scr   f32 [16]      @40704  (64)    -> 40768 dynamic
#define OFF_AM   33792
#define OFF_JP   38912
#define OFF_W    39936
#define OFF_SCR  40704
__global__ __launch_bounds__(256, 3) void kmain(const int* __restrict__ input_u,
                                                const int* __restrict__ input_i,
                                                const int* __restrict__ input_uf,
                                                const float* __restrict__ uidW,
                                                const float* __restrict__ iidW,
                                                const float* __restrict__ i_bias,
                                                const float* __restrict__ BA,
                                                const float* __restrict__ U_omega,
                                                const float* __restrict__ att_exp1,
                                                const float* __restrict__ ak,
                                                const float* __restrict__ ssum_ws,
                                                const unsigned short* __restrict__ fe_ws,
                                                const unsigned short* __restrict__ memT_ws,
                                                const unsigned short* __restrict__ watt_ws,
                                                float* __restrict__ out) {
    extern __shared__ char smem[];
    float* jpL  = (float*)(smem + OFF_JP);
    float* wL   = (float*)(smem + OFF_W);
    float* scr  = (float*)(smem + OFF_SCR);
    const int b = blockIdx.x, t = threadIdx.x;
    const int w = t >> 6, l = t & 63, q = l >> 4;

    // ---- front-load every global read this block needs (max MLP, no barrier yet) ----
    int iu = input_u[b], ii = input_i[b];
    float uidv = uidW[(size_t)iu * DIM + t];
    float iidv = iidW[(size_t)ii * DIM + t];
    float ib   = i_bias[ii];
    float ae00 = att_exp1[t * 2], ae01 = att_exp1[t * 2 + 1];
    float ae10 = att_exp1[(DIM + t) * 2], ae11 = att_exp1[(DIM + t) * 2 + 1];
    int uf_f = input_uf[b * NF + (t >> 2)];    // mask for ph1 (friend t>>2)
    int uf_t = input_uf[b * NF + (t & 63)];    // mask for ph5 (friend t, t<64)
    const float4* akp = (const float4*)(ak + (size_t)b * 2048);
    const float4* rp  = (const float4*)ssum_ws;
    float4 a0 = akp[2 * t], a1 = akp[2 * t + 1];
    float4 r0 = rp[2 * t],  r1 = rp[2 * t + 1];
    ushort4 feb[16];
#pragma unroll
    for (int i = 0; i < 16; i++)
        feb[i] = *(const ushort4*)(fe_ws + (size_t)b * 16384 + (w * 16 + i) * 256 + l * 4);

    // ph1: att_mem = mask * eak * rsum -> LDS bf16 (A-operand of f1 GEMM); no barrier needed first
    {
        float mk = (uf_f != USER_NUM) ? 1.0f : 0.0f;
        float v0 = mk * a0.x * r0.x;
        float v1 = mk * a0.y * r0.y;
        float v2 = mk * a0.z * r0.z;
        float v3 = mk * a0.w * r0.w;
        float v4 = mk * a1.x * r1.x;
        float v5 = mk * a1.y * r1.y;
        float v6 = mk * a1.z * r1.z;
        float v7 = mk * a1.w * r1.w;
        uint4 pk;
        pk.x = (unsigned)f2bf(v0) | ((unsigned)f2bf(v1) << 16);
        pk.y = (unsigned)f2bf(v2) | ((unsigned)f2bf(v3) << 16);
        pk.z = (unsigned)f2bf(v4) | ((unsigned)f2bf(v5) << 16);
        pk.w = (unsigned)f2bf(v6) | ((unsigned)f2bf(v7) << 16);
        *(uint4*)(smem + OFF_AM + (t >> 2) * 80 + (t & 3) * 16) = pk;
    }
    __syncthreads();

    // ph2: f1[64f x 256d] = am[64x32] @ Mem[32x256]  (wave w owns d in [64w,64w+64))
    {
        const uint4* mp = (const uint4*)memT_ws;   // [d][m] rows of 64B = 4 uint4
        bf16x8 aF[4];
#pragma unroll
        for (int ft = 0; ft < 4; ft++)
            aF[ft] = *(const bf16x8*)(smem + OFF_AM + (ft * 16 + (l & 15)) * 80 + q * 16);
#pragma unroll
        for (int dti = 0; dti < 4; dti++) {
            int dt = 4 * w + dti;
            bf16x8 bF = as_frag(mp[(dt * 16 + (l & 15)) * 4 + q]);
            int dcol = dt * 16 + (l & 15);
#pragma unroll
            for (int ft = 0; ft < 4; ft++) {
                f32x4 acc = {0.f, 0.f, 0.f, 0.f};
                acc = __builtin_amdgcn_mfma_f32_16x16x32_bf16(aF[ft], bF, acc, 0, 0, 0);
                int fbase = ft * 16 + q * 4;
#pragma unroll
                for (int r = 0; r < 4; r++)
                    *(unsigned short*)(smem + (fbase + r) * 528 + dcol * 2) = f2bf(acc[r]);
            }
        }
    }
    __syncthreads();

    // ph3: f2 = f1 * fe (fe prefetched at kernel start; mask already folded into fe)
    {
#pragma unroll
        for (int i = 0; i < 16; i++) {
            int f = w * 16 + i;
            ushort4* p = (ushort4*)(smem + f * 528 + l * 8);
            ushort4 fv = *p;
            ushort4 o4;
            o4.x = f2bf(bf2f(fv.x) * bf2f(feb[i].x));
            o4.y = f2bf(bf2f(fv.y) * bf2f(feb[i].y));
            o4.z = f2bf(bf2f(fv.z) * bf2f(feb[i].z));
            o4.w = f2bf(bf2f(fv.w) * bf2f(feb[i].w));
            *p = o4;
        }
    }
    __syncthreads();

    // ph4: H = relu(f2 @ WA + BA); logits j_f = sum_a H*Uw. Wave w owns a in [64w,64w+64).
    f32x4 acc[4][4];
    {
        f32x4 z = {0.f, 0.f, 0.f, 0.f};
#pragma unroll
        for (int ft = 0; ft < 4; ft++)
#pragma unroll
            for (int at = 0; at < 4; at++) acc[ft][at] = z;
    }
    {
        const uint4* wp = (const uint4*)watt_ws;   // [kt][a][kk]: kt*1024 + a*4 + q
        for (int kt = 0; kt < 8; kt++) {
            bf16x8 aF[4], bF[4];
#pragma unroll
            for (int ft = 0; ft < 4; ft++)
                aF[ft] = *(const bf16x8*)(smem + (ft * 16 + (l & 15)) * 528 + kt * 64 + q * 16);
#pragma unroll
            for (int at = 0; at < 4; at++)
                bF[at] = as_frag(wp[kt * 1024 + (64 * w + at * 16 + (l & 15)) * 4 + q]);
#pragma unroll
            for (int ft = 0; ft < 4; ft++)
#pragma unroll
                for (int at = 0; at < 4; at++)
                    acc[ft][at] = __builtin_amdgcn_mfma_f32_16x16x32_bf16(aF[ft], bF[at], acc[ft][at], 0, 0, 0);
        }
    }
    {
        float jp[16];
#pragma unroll
        for (int i = 0; i < 16; i++) jp[i] = 0.f;
#pragma unroll
        for (int at = 0; at < 4; at++) {
            int a = 64 * w + at * 16 + (l & 15);
            float ba = BA[a], uw = U_omega[a];
#pragma unroll
            for (int ft = 0; ft < 4; ft++)
#pragma unroll
                for (int r = 0; r < 4; r++) {
                    float h = fmaxf(acc[ft][at][r] + ba, 0.f);
                    jp[ft * 4 + r] += h * uw;
                }
        }
#pragma unroll
        for (int mask = 1; mask < 16; mask <<= 1)
#pragma unroll
            for (int i = 0; i < 16; i++) jp[i] += __shfl_xor(jp[i], mask, 64);
        if ((l & 15) == 0) {
#pragma unroll
            for (int ft = 0; ft < 4; ft++)
#pragma unroll
                for (int r = 0; r < 4; r++)
                    jpL[w * 64 + ft * 16 + q * 4 + r] = jp[ft * 4 + r];
        }
    }
    __syncthreads();

    // ph5: friend weights w_f = mask*exp(logit) / (sum + 1e-8)
    if (t < 64) {
        float logit = jpL[t] + jpL[64 + t] + jpL[128 + t] + jpL[192 + t];
        float jv = ((uf_t != USER_NUM) ? 1.0f : 0.0f) * __expf(logit);
        float s = jv;
#pragma unroll
        for (int o = 32; o; o >>= 1) s += __shfl_xor(s, o, 64);
        wL[t] = jv / (s + 1e-8f);
    }
    __syncthreads();

    // ph6: friend[d] = sum_f w_f * f2[f][d]
    float fr = 0.f;
#pragma unroll 8
    for (int f = 0; f < 64; f++)
        fr += wL[f] * bf2f(*(unsigned short*)(smem + f * 528 + t * 2));

    // ph7: user attention + score (two logits share one barrier pair)
    float user = uidv + fr;
    float2 ll = block_reduce_sum2(uidv * ae00 + user * ae10, uidv * ae01 + user * ae11, scr);
    float mx = fmaxf(ll.x, ll.y);
    float e0 = __expf(ll.x - mx), e1 = __expf(ll.y - mx);
    float rinv = 1.0f / (e0 + e1);
    float a0w = e0 * rinv, a1w = e1 * rinv;
    float sc = block_reduce_sum((uidv * a0w + user * a1w) * iidv, scr);
    if (t == 0) out[b] = sc + ib;
}

extern "C" void kernel_launch(void* const* d_in, const int* in_sizes, int n_in,
                              void* d_out, int out_size, void* d_ws, size_t ws_size,
                              hipStream_t stream) {
    const int*   input_u  = (const int*)d_in[0];
    const int*   input_i  = (const int*)d_in[1];
    const int*   input_uf = (const int*)d_in[2];
    const float* uidW     = (const float*)d_in[3];
    const float* iidW     = (const float*)d_in[4];
    const float* i_bias   = (const float*)d_in[5];
    const float* Key      = (const float*)d_in[6];
    const float* Mem      = (const float*)d_in[7];
    const float* WA       = (const float*)d_in[8];
    const float* BA       = (const float*)d_in[9];
    const float* U_omega  = (const float*)d_in[10];
    const float* att_exp1 = (const float*)d_in[11];
    float* out = (float*)d_out;
    char* ws = (char*)d_ws;

    float*          ak   = (float*)(ws + WS_AK);
    unsigned short* fe   = (unsigned short*)(ws + WS_FE);
    unsigned short* keyT = (unsigned short*)(ws + WS_KEYT);
    unsigned short* memT = (unsigned short*)(ws + WS_MEMT);
    unsigned short* watt = (unsigned short*)(ws + WS_WATT);
    float*          part = (float*)(ws + WS_PART);
    float*          ssum = (float*)(ws + WS_SSUM);

    hipLaunchKernelGGL(kprep, dim3(32), dim3(256), 0, stream, Key, keyT);
    hipLaunchKernelGGL(katt, dim3(BATCH), dim3(256), 34880, stream, input_u, input_uf, uidW, keyT, fe, ak);
    hipLaunchKernelGGL(ksum1, dim3(512), dim3(256), 0, stream, ak, part);
    hipLaunchKernelGGL(ksum2, dim3(8), dim3(256), 0, stream, part, ssum, Mem, WA, memT, watt);
    hipLaunchKernelGGL(kmain, dim3(BATCH), dim3(256), 40768, stream, input_u, input_i, input_uf,
                       uidW, iidW, i_bias, BA, U_omega, att_exp1, ak, ssum, fe, memT, watt, out);
}

// Round 2
// 771.289 us; speedup vs baseline: 1.0407x; 1.0259x over previous
//
#include <hip/hip_runtime.h>

#define USER_NUM 500000
#define BATCH 4096
#define NF 64
#define DIM 256
#define MEMN 32
#define ATTN 256

typedef short bf16x8 __attribute__((ext_vector_type(8)));
typedef float f32x4 __attribute__((ext_vector_type(4)));

// ---------- bf16 helpers (RNE) ----------
__device__ __forceinline__ unsigned short f2bf(float f) {
    unsigned u = __float_as_uint(f);
    u += 0x7FFFu + ((u >> 16) & 1u);
    return (unsigned short)(u >> 16);
}
__device__ __forceinline__ float bf2f(unsigned short s) {
    return __uint_as_float(((unsigned)s) << 16);
}
__device__ __forceinline__ bf16x8 as_frag(uint4 v) {
    return __builtin_bit_cast(bf16x8, v);
}

// two block reductions sharing one barrier pair
__device__ __forceinline__ float2 block_reduce_sum2(float a, float b, float* scr) {
#pragma unroll
    for (int o = 32; o; o >>= 1) {
        a += __shfl_xor(a, o, 64);
        b += __shfl_xor(b, o, 64);
    }
    __syncthreads();
    if ((threadIdx.x & 63) == 0) {
        scr[(threadIdx.x >> 6) * 2]     = a;
        scr[(threadIdx.x >> 6) * 2 + 1] = b;
    }
    __syncthreads();
    float2 r;
    r.x = scr[0] + scr[2] + scr[4] + scr[6];
    r.y = scr[1] + scr[3] + scr[5] + scr[7];
    return r;
}
__device__ __forceinline__ float block_reduce_sum(float v, float* scr) {
#pragma unroll
    for (int o = 32; o; o >>= 1) v += __shfl_xor(v, o, 64);
    __syncthreads();
    if ((threadIdx.x & 63) == 0) scr[threadIdx.x >> 6] = v;
    __syncthreads();
    return scr[0] + scr[1] + scr[2] + scr[3];
}

// ---------- ws offsets (bytes) ----------
#define WS_AK    0u            // bf16  [4096][64][32]     = 16777216  (holds exp(att_key), bf16)
#define WS_FE    33554432u     // bf16  [4096][64][256]    = 134217728 (masked fe)
#define WS_KEYT  167772160u    // bf16  [32][256]          = 16384  (KeyT[m][d])
#define WS_MEMT  167788544u    // bf16  [256][32]          = 16384  (MemT[d][m])
#define WS_WATT  167804928u    // bf16  [8][256][32]       = 131072 (WA k-tiled: [kt][a][kk])
#define WS_SSUM  168001536u    // float [2048]             = 8192   (holds sum_b exp)

// =============== kernel P: all constant prep + ssum zero ===============
// grid = 328 blocks * 256 = 83968 = 8192(keyT) + 8192(memT) + 65536(watt) + 2048(ssum zero)
__global__ __launch_bounds__(256) void kprep(const float* __restrict__ Key,
                                             const float* __restrict__ Mem,
                                             const float* __restrict__ WA,
                                             unsigned short* __restrict__ keyT,
                                             unsigned short* __restrict__ memT,
                                             unsigned short* __restrict__ watt,
                                             float* __restrict__ ssum) {
    int gid = blockIdx.x * 256 + threadIdx.x;
    if (gid < 8192) {                 // KeyT[m][d] = Key[d][m]
        int m = gid >> 8, d = gid & 255;
        keyT[gid] = f2bf(Key[d * 32 + m]);
    } else if (gid < 16384) {         // MemT[d][m] = Mem[m][d]
        int e = gid - 8192, d = e >> 5, m = e & 31;
        memT[e] = f2bf(Mem[m * 256 + d]);
    } else if (gid < 81920) {         // watt[kt][a][kk] = WA[kt*32+kk][a]
        int e = gid - 16384;
        int kt = e >> 13, r = e & 8191, a = r >> 5, kk = r & 31;
        watt[e] = f2bf(WA[(kt * 32 + kk) * 256 + a]);
    } else {                          // zero softmax-sum accumulator (atomics target)
        ssum[gid - 81920] = 0.f;
    }
}

// =============== kernel A: eak[b,f,m]=bf16(exp(att_key)) + fe_bf16 dump ===============
// LDS: cross bf16 [64][264] @0 -> 33792 dynamic. ONE barrier total.
__global__ __launch_bounds__(256, 4) void katt(const int* __restrict__ input_u,
                                               const int* __restrict__ input_uf,
                                               const float* __restrict__ uidW,
                                               const unsigned short* __restrict__ keyT_ws,
                                               unsigned short* __restrict__ fe_ws,
                                               unsigned short* __restrict__ ak) {
    extern __shared__ char smem[];
    const int b = blockIdx.x, t = threadIdx.x;
    const int w = t >> 6, l = t & 63, q = l >> 4;

    int iu   = input_u[b];
    int myuf = input_uf[b * NF + w * 16 + (l & 15)];
    // per-wave redundant uid row read (L1-hot, 1KB/wave) -> no cross-wave reduce, no barrier
    float4 u4 = ((const float4*)(uidW + (size_t)iu * DIM))[l];

    // prologue: issue first 8 friend-row gathers (latency overlaps uid normalize + early friends)
    float4 fv[8];
#pragma unroll
    for (int i = 0; i < 8; i++) {
        int idx = __shfl(myuf, i, 64);
        fv[i] = ((const float4*)(uidW + (size_t)idx * DIM))[l];
    }

    // wave-local uid L2-normalize (64 lanes x 4 elems = full 256-d row)
    float ssp = u4.x * u4.x + u4.y * u4.y + u4.z * u4.z + u4.w * u4.w;
#pragma unroll
    for (int o = 32; o; o >>= 1) ssp += __shfl_xor(ssp, o, 64);
    float inv = 1.0f / fmaxf(sqrtf(ssp), 1e-12f);
    float4 un4;
    un4.x = u4.x * inv; un4.y = u4.y * inv; un4.z = u4.z * inv; un4.w = u4.w * inv;

    // pipelined friend loop: iter i processes row i, issues row i+8
    float4 fv2[8];
#pragma unroll
    for (int i = 0; i < 16; i++) {
        if (i < 8) {
            int idx2 = __shfl(myuf, i + 8, 64);
            fv2[i] = ((const float4*)(uidW + (size_t)idx2 * DIM))[l];
        }
        float4 cur;
        if (i < 8) cur = fv[i]; else cur = fv2[i - 8];
        int f = w * 16 + i;
        int idc = __shfl(myuf, i, 64);
        float mk = (idc != USER_NUM) ? 1.0f : 0.0f;
        float x = cur.x * mk, y = cur.y * mk, z = cur.z * mk, ww = cur.w * mk;
        float s2 = x * x + y * y + z * z + ww * ww;
#pragma unroll
        for (int o = 32; o; o >>= 1) s2 += __shfl_xor(s2, o, 64);
        float rn = 1.0f / fmaxf(sqrtf(s2), 1e-12f);
        // masked fe -> ws (bf16, sequential)
        ushort4 fb;
        fb.x = f2bf(x); fb.y = f2bf(y); fb.z = f2bf(z); fb.w = f2bf(ww);
        *(ushort4*)(fe_ws + (size_t)b * 16384 + f * 256 + l * 4) = fb;
        // cross = uid_n * fe_n -> LDS
        ushort4 o4;
        o4.x = f2bf(un4.x * x * rn);
        o4.y = f2bf(un4.y * y * rn);
        o4.z = f2bf(un4.z * z * rn);
        o4.w = f2bf(un4.w * ww * rn);
        *(ushort4*)(smem + f * 528 + l * 8) = o4;
    }
    __syncthreads();

    // MFMA: att_key[64f x 32m] = cross[64x256] @ Key[256x32]; wave w owns f-tile w.
    const uint4* kp = (const uint4*)keyT_ws;   // [m][d] rows of 512B = 32 uint4
    f32x4 acc0 = {0.f, 0.f, 0.f, 0.f}, acc1 = {0.f, 0.f, 0.f, 0.f};
#pragma unroll
    for (int kt = 0; kt < 8; kt++) {
        bf16x8 aF = *(const bf16x8*)(smem + (w * 16 + (l & 15)) * 528 + kt * 64 + q * 16);
        bf16x8 b0 = as_frag(kp[(l & 15) * 32 + kt * 4 + q]);
        bf16x8 b1 = as_frag(kp[((l & 15) + 16) * 32 + kt * 4 + q]);
        acc0 = __builtin_amdgcn_mfma_f32_16x16x32_bf16(aF, b0, acc0, 0, 0, 0);
        acc1 = __builtin_amdgcn_mfma_f32_16x16x32_bf16(aF, b1, acc1, 0, 0, 0);
    }
    {
        int fbase = w * 16 + q * 4;
        int m = l & 15;
#pragma unroll
        for (int r = 0; r < 4; r++) {
            unsigned short* row = ak + ((size_t)b * NF + fbase + r) * MEMN;
            row[m]      = f2bf(__expf(acc0[r]));
            row[m + 16] = f2bf(__expf(acc1[r]));
        }
    }
}

// =============== kernel B: ssum[f,m] += sum_b eak[b,f,m]  (atomic fold) ===============
__global__ __launch_bounds__(256) void ksum1(const unsigned short* __restrict__ ak, float* __restrict__ ssum) {
    __shared__ float pl[256];
    int bid = blockIdx.x;               // 512 = 64 f * 8 chunks
    int f = bid >> 3, c = bid & 7;
    int t = threadIdx.x, m = t & 31, g = t >> 5;
    float s = 0.f;
    size_t base = ((size_t)(c * 512 + g) * NF + f) * MEMN + m;
#pragma unroll 8
    for (int i = 0; i < 64; i++) {      // b = c*512 + g + 8*i
        s += bf2f(ak[base]);
        base += (size_t)8 * NF * MEMN;
    }
    pl[t] = s;
    __syncthreads();
    if (t < 32) {
        float tot = 0.f;
#pragma unroll
        for (int gg = 0; gg < 8; gg++) tot += pl[gg * 32 + t];
        atomicAdd(&ssum[f * 32 + t], tot);
    }
}

// =============== kernel C: everything after the batch softmax (one block per b) ===============
// LDS layout (bytes):
//   f1f2 bf16 [64][264] @0      (33792)   f1 then overwritten by f2
//   am   bf16 [64][40]  @33792  (5120)
//   jpart f32 [4][64]   @38912  (1024)
//   scr   f32 [16]      @39936  (64)    -> 40000 dynamic
#define OFF_AM   33792
#define OFF_JP   38912
#define OFF_SCR  39936
__global__ __launch_bounds__(256, 3) void kmain(const int* __restrict__ input_u,
                                                const int* __restrict__ input_i,
                                                const int* __restrict__ input_uf,
                                                const float* __restrict__ uidW,
                                                const float* __restrict__ iidW,
                                                const float* __restrict__ i_bias,
                                                const float* __restrict__ BA,
                                                const float* __restrict__ U_omega,
                                                const float* __restrict__ att_exp1,
                                                const unsigned short* __restrict__ ak,
                                                const float* __restrict__ ssum_ws,
                                                const unsigned short* __restrict__ fe_ws,
                                                const unsigned short* __restrict__ memT_ws,
                                                const unsigned short* __restrict__ watt_ws,
                                                float* __restrict__ out) {
    extern __shared__ char smem[];
    float* jpL  = (float*)(smem + OFF_JP);
    float* scr  = (float*)(smem + OFF_SCR);
    const int b = blockIdx.x, t = threadIdx.x;
    const int w = t >> 6, l = t & 63, q = l >> 4;

    // ---- front-load every global read this block needs (max MLP, no barrier yet) ----
    int iu = input_u[b], ii = input_i[b];
    float uidv = uidW[(size_t)iu * DIM + t];
    float iidv = iidW[(size_t)ii * DIM + t];
    float ib   = i_bias[ii];
    float ae00 = att_exp1[t * 2], ae01 = att_exp1[t * 2 + 1];
    float ae10 = att_exp1[(DIM + t) * 2], ae11 = att_exp1[(DIM + t) * 2 + 1];
    int uf_f = input_uf[b * NF + (t >> 2)];    // mask for ph1 (friend t>>2)
    int uf_t = input_uf[b * NF + (t & 63)];    // mask for ph5 (friend l)
    const uint4* akp = (const uint4*)(ak + (size_t)b * 2048);
    uint4 av = akp[t];                          // 8 bf16 exp values for (f = t>>2, m = (t&3)*8 ..+7)
    const float4* sp = (const float4*)ssum_ws;
    float4 s0 = sp[2 * t], s1 = sp[2 * t + 1];
    ushort4 feb[16];
#pragma unroll
    for (int i = 0; i < 16; i++)
        feb[i] = *(const ushort4*)(fe_ws + (size_t)b * 16384 + (w * 16 + i) * 256 + l * 4);

    // ph1: att_mem = mask * eak / ssum -> LDS bf16 (A-operand of f1 GEMM)
    {
        float mk = (uf_f != USER_NUM) ? 1.0f : 0.0f;
        float v0 = mk * bf2f((unsigned short)(av.x & 0xffff)) * __builtin_amdgcn_rcpf(s0.x);
        float v1 = mk * bf2f((unsigned short)(av.x >> 16))    * __builtin_amdgcn_rcpf(s0.y);
        float v2 = mk * bf2f((unsigned short)(av.y & 0xffff)) * __builtin_amdgcn_rcpf(s0.z);
        float v3 = mk * bf2f((unsigned short)(av.y >> 16))    * __builtin_amdgcn_rcpf(s0.w);
        float v4 = mk * bf2f((unsigned short)(av.z & 0xffff)) * __builtin_amdgcn_rcpf(s1.x);
        float v5 = mk * bf2f((unsigned short)(av.z >> 16))    * __builtin_amdgcn_rcpf(s1.y);
        float v6 = mk * bf2f((unsigned short)(av.w & 0xffff)) * __builtin_amdgcn_rcpf(s1.z);
        float v7 = mk * bf2f((unsigned short)(av.w >> 16))    * __builtin_amdgcn_rcpf(s1.w);
        uint4 pk;
        pk.x = (unsigned)f2bf(v0) | ((unsigned)f2bf(v1) << 16);
        pk.y = (unsigned)f2bf(v2) | ((unsigned)f2bf(v3) << 16);
        pk.z = (unsigned)f2bf(v4) | ((unsigned)f2bf(v5) << 16);
        pk.w = (unsigned)f2bf(v6) | ((unsigned)f2bf(v7) << 16);
        *(uint4*)(smem + OFF_AM + (t >> 2) * 80 + (t & 3) * 16) = pk;
    }
    __syncthreads();

    // ph2: f1[64f x 256d] = am[64x32] @ Mem[32x256]  (wave w owns d in [64w,64w+64))
    {
        const uint4* mp = (const uint4*)memT_ws;   // [d][m] rows of 64B = 4 uint4
        bf16x8 aF[4];
#pragma unroll
        for (int ft = 0; ft < 4; ft++)
            aF[ft] = *(const bf16x8*)(smem + OFF_AM + (ft * 16 + (l & 15)) * 80 + q * 16);
#pragma unroll
        for (int dti = 0; dti < 4; dti++) {
            int dt = 4 * w + dti;
            bf16x8 bF = as_frag(mp[(dt * 16 + (l & 15)) * 4 + q]);
            int dcol = dt * 16 + (l & 15);
#pragma unroll
            for (int ft = 0; ft < 4; ft++) {
                f32x4 acc = {0.f, 0.f, 0.f, 0.f};
                acc = __builtin_amdgcn_mfma_f32_16x16x32_bf16(aF[ft], bF, acc, 0, 0, 0);
                int fbase = ft * 16 + q * 4;
#pragma unroll
                for (int r = 0; r < 4; r++)
                    *(unsigned short*)(smem + (fbase + r) * 528 + dcol * 2) = f2bf(acc[r]);
            }
        }
    }
    __syncthreads();

    // ph3: f2 = f1 * fe (fe prefetched at kernel start; mask already folded into fe)
    {
#pragma unroll
        for (int i = 0; i < 16; i++) {
            int f = w * 16 + i;
            ushort4* p = (ushort4*)(smem + f * 528 + l * 8);
            ushort4 fv = *p;
            ushort4 o4;
            o4.x = f2bf(bf2f(fv.x) * bf2f(feb[i].x));
            o4.y = f2bf(bf2f(fv.y) * bf2f(feb[i].y));
            o4.z = f2bf(bf2f(fv.z) * bf2f(feb[i].z));
            o4.w = f2bf(bf2f(fv.w) * bf2f(feb[i].w));
            *p = o4;
        }
    }
    __syncthreads();

    // ph4: H = relu(f2 @ WA + BA); logits j_f = sum_a H*Uw. Wave w owns a in [64w,64w+64).
    f32x4 acc[4][4];
    {
        f32x4 z = {0.f, 0.f, 0.f, 0.f};
#pragma unroll
        for (int ft = 0; ft < 4; ft++)
#pragma unroll
            for (int at = 0; at < 4; at++) acc[ft][at] = z;
    }
    {
        const uint4* wp = (const uint4*)watt_ws;   // [kt][a][kk]: kt*1024 + a*4 + q
        for (int kt = 0; kt < 8; kt++) {
            bf16x8 aF[4], bF[4];
#pragma unroll
            for (int ft = 0; ft < 4; ft++)
                aF[ft] = *(const bf16x8*)(smem + (ft * 16 + (l & 15)) * 528 + kt * 64 + q * 16);
#pragma unroll
            for (int at = 0; at < 4; at++)
                bF[at] = as_frag(wp[kt * 1024 + (64 * w + at * 16 + (l & 15)) * 4 + q]);
#pragma unroll
            for (int ft = 0; ft < 4; ft++)
#pragma unroll
                for (int at = 0; at < 4; at++)
                    acc[ft][at] = __builtin_amdgcn_mfma_f32_16x16x32_bf16(aF[ft], bF[at], acc[ft][at], 0, 0, 0);
        }
    }
    {
        float jp[16];
#pragma unroll
        for (int i = 0; i < 16; i++) jp[i] = 0.f;
#pragma unroll
        for (int at = 0; at < 4; at++) {
            int a = 64 * w + at * 16 + (l & 15);
            float ba = BA[a], uw = U_omega[a];
#pragma unroll
            for (int ft = 0; ft < 4; ft++)
#pragma unroll
                for (int r = 0; r < 4; r++) {
                    float h = fmaxf(acc[ft][at][r] + ba, 0.f);
                    jp[ft * 4 + r] += h * uw;
                }
        }
#pragma unroll
        for (int mask = 1; mask < 16; mask <<= 1)
#pragma unroll
            for (int i = 0; i < 16; i++) jp[i] += __shfl_xor(jp[i], mask, 64);
        if ((l & 15) == 0) {
#pragma unroll
            for (int ft = 0; ft < 4; ft++)
#pragma unroll
                for (int r = 0; r < 4; r++)
                    jpL[w * 64 + ft * 16 + q * 4 + r] = jp[ft * 4 + r];
        }
    }
    __syncthreads();

    // ph5+6 fused, per-wave redundant: friend weights via shfl broadcast (no barrier between)
    float fr;
    {
        float logit = jpL[l] + jpL[64 + l] + jpL[128 + l] + jpL[192 + l];
        float jv = ((uf_t != USER_NUM) ? 1.0f : 0.0f) * __expf(logit);
        float sj = jv;
#pragma unroll
        for (int o = 32; o; o >>= 1) sj += __shfl_xor(sj, o, 64);
        float wv = jv / (sj + 1e-8f);     // lane l holds weight of friend l
        fr = 0.f;
#pragma unroll 8
        for (int f = 0; f < 64; f++)
            fr += __shfl(wv, f, 64) * bf2f(*(unsigned short*)(smem + f * 528 + t * 2));
    }

    // ph7: user attention + score (two logits share one barrier pair)
    float user = uidv + fr;
    float2 ll = block_reduce_sum2(uidv * ae00 + user * ae10, uidv * ae01 + user * ae11, scr);
    float mx = fmaxf(ll.x, ll.y);
    float e0 = __expf(ll.x - mx), e1 = __expf(ll.y - mx);
    float rinv = 1.0f / (e0 + e1);
    float a0w = e0 * rinv, a1w = e1 * rinv;
    float sc = block_reduce_sum((uidv * a0w + user * a1w) * iidv, scr);
    if (t == 0) out[b] = sc + ib;
}

extern "C" void kernel_launch(void* const* d_in, const int* in_sizes, int n_in,
                              void* d_out, int out_size, void* d_ws, size_t ws_size,
                              hipStream_t stream) {
    const int*   input_u  = (const int*)d_in[0];
    const int*   input_i  = (const int*)d_in[1];
    const int*   input_uf = (const int*)d_in[2];
    const float* uidW     = (const float*)d_in[3];
    const float* iidW     = (const float*)d_in[4];
    const float* i_bias   = (const float*)d_in[5];
    const float* Key      = (const float*)d_in[6];
    const float* Mem      = (const float*)d_in[7];
    const float* WA       = (const float*)d_in[8];
    const float* BA       = (const float*)d_in[9];
    const float* U_omega  = (const float*)d_in[10];
    const float* att_exp1 = (const float*)d_in[11];
    float* out = (float*)d_out;
    char* ws = (char*)d_ws;

    unsigned short* ak   = (unsigned short*)(ws + WS_AK);
    unsigned short* fe   = (unsigned short*)(ws + WS_FE);
    unsigned short* keyT = (unsigned short*)(ws + WS_KEYT);
    unsigned short* memT = (unsigned short*)(ws + WS_MEMT);
    unsigned short* watt = (unsigned short*)(ws + WS_WATT);
    float*          ssum = (float*)(ws + WS_SSUM);

    hipLaunchKernelGGL(kprep, dim3(328), dim3(256), 0, stream, Key, Mem, WA, keyT, memT, watt, ssum);
    hipLaunchKernelGGL(katt, dim3(BATCH), dim3(256), 33792, stream, input_u, input_uf, uidW, keyT, fe, ak);
    hipLaunchKernelGGL(ksum1, dim3(512), dim3(256), 0, stream, ak, ssum);
    hipLaunchKernelGGL(kmain, dim3(BATCH), dim3(256), 40000, stream, input_u, input_i, input_uf,
                       uidW, iidW, i_bias, BA, U_omega, att_exp1, ak, ssum, fe, memT, watt, out);
}